// Round 11
// baseline (305.331 us; speedup 1.0000x reference)
//
#include <hip/hip_runtime.h>
#include <math.h>

#define NM    6400
#define DT    64            // samples per chunk == lanes per wave
#define NCH   352           // padded chunk count (345 real)
#define CGRP  8             // chunks per gen thread
#define NCG   (NCH / CGRP)  // 44
#define CB    16            // chunks per gemm block (4 waves x 4)
#define MB    64            // modes per gemm tile
#define MGY   (NM / MB)     // 100

#define GEN_A (NCG * NM)            // statePair items (mode-major within group)
#define GEN_B (NM * 8)              // cdsd items (8 dt per thread)

static __device__ __forceinline__ float softplusf(float x) {
    return log1pf(expf(-fabsf(x))) + fmaxf(x, 0.0f);
}
static __device__ __forceinline__ float sigmoidf(float x) {
    return 1.0f / (1.0f + expf(-x));
}

// EXACT fp32 sequence used by all passing rounds: mode id -> (A, omega, sigma)
static __device__ __forceinline__ void mode_const(
    int id, float mu_raw, float Dmu_raw, float T0mu_raw,
    float Ly_raw, float xo_raw, float yo_raw,
    float& A, float& omega, float& sigma)
{
    const float KF   = 1.0f / 44100.0f;
    const float PI_F = (float)M_PI;
    const double om2sq = (2.0 * M_PI * 500.0) * (2.0 * M_PI * 500.0);
    const float ALPHA_F  = (float)(3.0 * M_LN10 / om2sq * (om2sq / 6.0));
    const float BETA_F   = (float)(3.0 * M_LN10 / om2sq * (1.0 - 1.0 / 6.0));
    const float MAX_OM_F = (float)(10000.0 * 2.0 * M_PI);
    const float MIN_OM_F = (float)(20.0 * 2.0 * M_PI);
    const float KK_F     = (float)((1.0 / 44100.0) * (1.0 / 44100.0));

    float mu   = (softplusf(mu_raw)   + 1e-4f) * 2.43f;
    float Dmu  = (softplusf(Dmu_raw)  + 1e-4f) * 0.002452f;
    float T0mu = (softplusf(T0mu_raw) + 1e-4f) * 0.004115f;
    float Ly   = 1.1f + 2.9f * sigmoidf(Ly_raw);
    float xo   = 0.245f + 0.255f * sigmoidf(xo_raw);
    float yo   = __fadd_rn(__fmul_rn(0.51f, Ly),
                           __fmul_rn(__fmul_rn(0.49f, Ly), sigmoidf(yo_raw)));

    float mf = (float)(id / 80 + 1);
    float nf = (float)(id % 80 + 1);

    float am = __fmul_rn(__fmul_rn(mf, PI_F), 2.0f);
    float bn = __fdiv_rn(__fmul_rn(nf, PI_F), Ly);
    float g1 = __fadd_rn(__fmul_rn(am, am), __fmul_rn(bn, bn));
    float omega_sq = __fadd_rn(__fmul_rn(T0mu, g1),
                               __fmul_rn(__fmul_rn(Dmu, g1), g1));
    omega = sqrtf(fmaxf(omega_sq, 0.0f));
    float valid = (omega <= MAX_OM_F && omega >= MIN_OM_F) ? 1.0f : 0.0f;

    float xi_pi = (float)(0.05 * M_PI);
    float yi = __fmul_rn(0.1f, Ly);
    float InW = __fmul_rn(
        cosf(__fmul_rn(__fmul_rn(xi_pi, mf), 2.0f)),
        cosf(__fdiv_rn(__fmul_rn(__fmul_rn(yi, PI_F), nf), Ly)));
    float OutW = __fmul_rn(
        cosf(__fmul_rn(__fmul_rn(__fmul_rn(xo, PI_F), mf), 2.0f)),
        cosf(__fdiv_rn(__fmul_rn(__fmul_rn(yo, PI_F), nf), Ly)));

    sigma = __fadd_rn(ALPHA_F, __fmul_rn(BETA_F, __fmul_rn(omega, omega)));
    float ms = __fmul_rn(__fmul_rn(__fmul_rn(0.25f, mu), 0.5f), Ly);
    float P = __fmul_rn(
        __fdiv_rn(__fmul_rn(__fmul_rn(__fmul_rn(OutW, InW), KK_F),
                            expf(__fmul_rn(-sigma, KF))),
                  ms),
        valid);
    float den = __fadd_rn(sinf(__fmul_rn(omega, KF)), 1e-8f);
    A = __fdiv_rn(P, den);
}

// Fully parallel generation (R10's setup_gen was 25 blocks doing 88-step
// SERIAL double chains -> ~50us; this is one thread per element group):
//  A: 281.6K threads -> statePair[c][m] = {S,C} closed-form (8 chunks each)
//  B: 51.2K threads  -> cdsdR/I[m][dt] = r^dt closed-form (8 dt each)
//  C: zero out[] and cnt
__global__ __launch_bounds__(256) void gen_kernel(
    const float* __restrict__ mu_raw, const float* __restrict__ Dmu_raw,
    const float* __restrict__ T0mu_raw, const float* __restrict__ Ly_raw,
    const float* __restrict__ xo_raw, const float* __restrict__ yo_raw,
    float2* __restrict__ statePair,
    float* __restrict__ cdsdR, float* __restrict__ cdsdI,
    float* __restrict__ out, unsigned int* __restrict__ cnt, int T)
{
    const float  KF     = 1.0f / 44100.0f;
    const double Kd     = 1.0 / 44100.0;
    const double TWO_PI = 6.283185307179586476925286766559;
    const double I2PI   = 0.15915494309189533576888376337251;

    int idx = blockIdx.x * blockDim.x + threadIdx.x;
    float mur = mu_raw[0], dmur = Dmu_raw[0], t0mur = T0mu_raw[0];
    float lyr = Ly_raw[0], xorw = xo_raw[0], yorw = yo_raw[0];

    if (idx < GEN_A) {
        int cg = idx / NM, m = idx - cg * NM;      // consecutive idx -> consecutive m
        float A, w, sg;
        mode_const(m, mur, dmur, t0mur, lyr, xorw, yorw, A, w, sg);
        #pragma unroll
        for (int i = 0; i < CGRP; ++i) {
            int c  = cg * CGRP + i;
            int t0 = c * DT;
            double ph = (double)t0 * (double)w * Kd;
            double q  = rint(ph * I2PI);
            float  r  = (float)fma(-q, TWO_PI, ph);
            float s0, c0;
            __sincosf(r, &s0, &c0);
            float env = A * __expf(-sg * (float)(t0 - 1) * KF);
            statePair[(size_t)c * NM + m] = make_float2(env * s0, env * c0);
        }
    } else if (idx < GEN_A + GEN_B) {
        int j = idx - GEN_A;
        int m = j >> 3, dtg = j & 7;
        float A, w, sg;
        mode_const(m, mur, dmur, t0mur, lyr, xorw, yorw, A, w, sg);
        (void)A;
        #pragma unroll
        for (int i = 0; i < 8; ++i) {
            int dt = dtg * 8 + i;
            double ph = (double)dt * (double)w * Kd;
            double q  = rint(ph * I2PI);
            float  r  = (float)fma(-q, TWO_PI, ph);
            float sr, cr;
            __sincosf(r, &sr, &cr);
            float dec = __expf(-sg * (float)dt * KF);
            cdsdR[m * DT + dt] = dec * cr;
            cdsdI[m * DT + dt] = dec * sr;
        }
    } else {
        int k = idx - GEN_A - GEN_B;
        if (k < T) out[k] = 0.0f;
        if (k == 0) cnt[0] = 0u;
    }
}

// out[64c+dt] += sum_{m in tile} S*Re(r^dt) + C*Im(r^dt); lane = dt.
// LDS planes m-major (2-way bank alias = free); states read as float4 per
// 2 modes (broadcast, halved VMEM issue). Last block (device counter)
// normalizes: peak |out| then divide. 2 graph nodes total.
__global__ __launch_bounds__(256) void gemm_norm_kernel(
    const float2* __restrict__ statePair,
    const float* __restrict__ cdsdR, const float* __restrict__ cdsdI,
    float* __restrict__ out, unsigned int* __restrict__ cnt, int T)
{
    __shared__ float tR[MB * DT], tI[MB * DT];    // 16 KB + 16 KB
    const int tid = threadIdx.x;
    const int mBase = blockIdx.y * MB;

    {   // stage tiles: contiguous 16 KB each, float4-coalesced
        const float4* sR = (const float4*)(cdsdR + mBase * DT);
        const float4* sI = (const float4*)(cdsdI + mBase * DT);
        float4* dR = (float4*)tR;
        float4* dI = (float4*)tI;
        #pragma unroll
        for (int i = 0; i < (MB * DT / 4) / 256; ++i) {
            dR[i * 256 + tid] = sR[i * 256 + tid];
            dI[i * 256 + tid] = sI[i * 256 + tid];
        }
    }
    __syncthreads();

    const int wave = tid >> 6, lane = tid & 63;
    const int c0 = blockIdx.x * CB + wave * 4;
    const float2* r0 = statePair + (size_t)c0 * NM + mBase;
    const float2* r1 = r0 + NM;
    const float2* r2 = r0 + 2 * (size_t)NM;
    const float2* r3 = r0 + 3 * (size_t)NM;

    float a0 = 0.0f, a1 = 0.0f, a2 = 0.0f, a3 = 0.0f;
    #pragma unroll 8
    for (int m = 0; m < MB; m += 2) {
        float wR0 = tR[m * DT + lane],       wI0 = tI[m * DT + lane];
        float wR1 = tR[(m + 1) * DT + lane], wI1 = tI[(m + 1) * DT + lane];
        float4 s0 = *(const float4*)(r0 + m);   // {S_m, C_m, S_m+1, C_m+1}
        float4 s1 = *(const float4*)(r1 + m);
        float4 s2 = *(const float4*)(r2 + m);
        float4 s3 = *(const float4*)(r3 + m);
        a0 = __fmaf_rn(s0.x, wR0, a0); a0 = __fmaf_rn(s0.y, wI0, a0);
        a0 = __fmaf_rn(s0.z, wR1, a0); a0 = __fmaf_rn(s0.w, wI1, a0);
        a1 = __fmaf_rn(s1.x, wR0, a1); a1 = __fmaf_rn(s1.y, wI0, a1);
        a1 = __fmaf_rn(s1.z, wR1, a1); a1 = __fmaf_rn(s1.w, wI1, a1);
        a2 = __fmaf_rn(s2.x, wR0, a2); a2 = __fmaf_rn(s2.y, wI0, a2);
        a2 = __fmaf_rn(s2.z, wR1, a2); a2 = __fmaf_rn(s2.w, wI1, a2);
        a3 = __fmaf_rn(s3.x, wR0, a3); a3 = __fmaf_rn(s3.y, wI0, a3);
        a3 = __fmaf_rn(s3.z, wR1, a3); a3 = __fmaf_rn(s3.w, wI1, a3);
    }

    int t = c0 * DT + lane;
    if (t          < T) atomicAdd(&out[t],          a0);
    if (t +     DT < T) atomicAdd(&out[t +     DT], a1);
    if (t + 2 * DT < T) atomicAdd(&out[t + 2 * DT], a2);
    if (t + 3 * DT < T) atomicAdd(&out[t + 3 * DT], a3);

    // ---- last-block normalization ----
    __threadfence();
    __syncthreads();
    __shared__ int sLast;
    __shared__ float red[4];
    if (tid == 0) {
        unsigned int old = atomicAdd(cnt, 1u);
        sLast = (old == gridDim.x * gridDim.y - 1) ? 1 : 0;
    }
    __syncthreads();
    if (sLast) {
        __threadfence();
        float mx = 0.0f;
        for (int i = tid; i < T; i += 256) mx = fmaxf(mx, fabsf(out[i]));
        #pragma unroll
        for (int off = 32; off > 0; off >>= 1)
            mx = fmaxf(mx, __shfl_xor(mx, off, 64));
        if (lane == 0) red[wave] = mx;
        __syncthreads();
        float pk = fmaxf(fmaxf(red[0], red[1]), fmaxf(red[2], red[3])) + 1e-8f;
        for (int i = tid; i < T; i += 256) out[i] = __fdiv_rn(out[i], pk);
    }
}

extern "C" void kernel_launch(void* const* d_in, const int* in_sizes, int n_in,
                              void* d_out, int out_size, void* d_ws, size_t ws_size,
                              hipStream_t stream)
{
    const float* mu   = (const float*)d_in[0];
    const float* Dmu  = (const float*)d_in[1];
    const float* T0mu = (const float*)d_in[2];
    const float* Lyr  = (const float*)d_in[3];
    const float* xor_ = (const float*)d_in[4];
    const float* yor_ = (const float*)d_in[5];
    float* out = (float*)d_out;

    float2* statePair = (float2*)d_ws;                         // 352*6400*8 = 18.0 MB
    float*  cdsdR     = (float*)(statePair + (size_t)NCH * NM);
    float*  cdsdI     = cdsdR + (size_t)NM * DT;               // 2 x 1.64 MB
    unsigned int* cnt = (unsigned int*)(cdsdI + (size_t)NM * DT);

    int T = out_size;
    int genItems = GEN_A + GEN_B + T;

    gen_kernel<<<(genItems + 255) / 256, 256, 0, stream>>>(
        mu, Dmu, T0mu, Lyr, xor_, yor_, statePair, cdsdR, cdsdI, out, cnt, T);
    gemm_norm_kernel<<<dim3(NCH / CB, MGY), 256, 0, stream>>>(
        statePair, cdsdR, cdsdI, out, cnt, T);
}

// Round 12
// 147.798 us; speedup vs baseline: 2.0659x; 2.0659x over previous
//
#include <hip/hip_runtime.h>
#include <math.h>

#define NM    6400
#define DT    64            // samples per chunk == lanes per wave
#define NCH   352           // padded chunk count (345 real)
#define NCHP  (NCH * DT + 64)  // padded partial plane stride (breaks 2^k aliasing)
#define CGRP  8             // chunks per gen thread
#define NCG   (NCH / CGRP)  // 44
#define CB    16            // chunks per gemm block (4 waves x 4)
#define MB    64            // modes per gemm tile
#define MGY   (NM / MB)     // 100

#define GEN_A (NCG * NM)    // statePair gen threads
#define GEN_B (NM * 8)      // cdsd gen threads (8 dt each)

static __device__ __forceinline__ float softplusf(float x) {
    return log1pf(expf(-fabsf(x))) + fmaxf(x, 0.0f);
}
static __device__ __forceinline__ float sigmoidf(float x) {
    return 1.0f / (1.0f + expf(-x));
}

// EXACT fp32 sequence used by all passing rounds: mode id -> (A, omega, sigma)
static __device__ __forceinline__ void mode_const(
    int id, float mu_raw, float Dmu_raw, float T0mu_raw,
    float Ly_raw, float xo_raw, float yo_raw,
    float& A, float& omega, float& sigma)
{
    const float KF   = 1.0f / 44100.0f;
    const float PI_F = (float)M_PI;
    const double om2sq = (2.0 * M_PI * 500.0) * (2.0 * M_PI * 500.0);
    const float ALPHA_F  = (float)(3.0 * M_LN10 / om2sq * (om2sq / 6.0));
    const float BETA_F   = (float)(3.0 * M_LN10 / om2sq * (1.0 - 1.0 / 6.0));
    const float MAX_OM_F = (float)(10000.0 * 2.0 * M_PI);
    const float MIN_OM_F = (float)(20.0 * 2.0 * M_PI);
    const float KK_F     = (float)((1.0 / 44100.0) * (1.0 / 44100.0));

    float mu   = (softplusf(mu_raw)   + 1e-4f) * 2.43f;
    float Dmu  = (softplusf(Dmu_raw)  + 1e-4f) * 0.002452f;
    float T0mu = (softplusf(T0mu_raw) + 1e-4f) * 0.004115f;
    float Ly   = 1.1f + 2.9f * sigmoidf(Ly_raw);
    float xo   = 0.245f + 0.255f * sigmoidf(xo_raw);
    float yo   = __fadd_rn(__fmul_rn(0.51f, Ly),
                           __fmul_rn(__fmul_rn(0.49f, Ly), sigmoidf(yo_raw)));

    float mf = (float)(id / 80 + 1);
    float nf = (float)(id % 80 + 1);

    float am = __fmul_rn(__fmul_rn(mf, PI_F), 2.0f);
    float bn = __fdiv_rn(__fmul_rn(nf, PI_F), Ly);
    float g1 = __fadd_rn(__fmul_rn(am, am), __fmul_rn(bn, bn));
    float omega_sq = __fadd_rn(__fmul_rn(T0mu, g1),
                               __fmul_rn(__fmul_rn(Dmu, g1), g1));
    omega = sqrtf(fmaxf(omega_sq, 0.0f));
    float valid = (omega <= MAX_OM_F && omega >= MIN_OM_F) ? 1.0f : 0.0f;

    float xi_pi = (float)(0.05 * M_PI);
    float yi = __fmul_rn(0.1f, Ly);
    float InW = __fmul_rn(
        cosf(__fmul_rn(__fmul_rn(xi_pi, mf), 2.0f)),
        cosf(__fdiv_rn(__fmul_rn(__fmul_rn(yi, PI_F), nf), Ly)));
    float OutW = __fmul_rn(
        cosf(__fmul_rn(__fmul_rn(__fmul_rn(xo, PI_F), mf), 2.0f)),
        cosf(__fdiv_rn(__fmul_rn(__fmul_rn(yo, PI_F), nf), Ly)));

    sigma = __fadd_rn(ALPHA_F, __fmul_rn(BETA_F, __fmul_rn(omega, omega)));
    float ms = __fmul_rn(__fmul_rn(__fmul_rn(0.25f, mu), 0.5f), Ly);
    float P = __fmul_rn(
        __fdiv_rn(__fmul_rn(__fmul_rn(__fmul_rn(OutW, InW), KK_F),
                            expf(__fmul_rn(-sigma, KF))),
                  ms),
        valid);
    float den = __fadd_rn(sinf(__fmul_rn(omega, KF)), 1e-8f);
    A = __fdiv_rn(P, den);
}

// Fully parallel generation, ~333K threads:
//  A: statePair[c][m] = {S,C} at t0=64c, closed-form (8 chunks/thread)
//  B: cdsdR/I[m][dt] = decay*cis(omega*dt*K), dt=0..63 (8 dt/thread)
//  C: zero cnt + peakBits
__global__ __launch_bounds__(256) void gen_kernel(
    const float* __restrict__ mu_raw, const float* __restrict__ Dmu_raw,
    const float* __restrict__ T0mu_raw, const float* __restrict__ Ly_raw,
    const float* __restrict__ xo_raw, const float* __restrict__ yo_raw,
    float2* __restrict__ statePair,
    float* __restrict__ cdsdR, float* __restrict__ cdsdI,
    unsigned int* __restrict__ cnt, unsigned int* __restrict__ peakBits)
{
    const float  KF     = 1.0f / 44100.0f;
    const double Kd     = 1.0 / 44100.0;
    const double TWO_PI = 6.283185307179586476925286766559;
    const double I2PI   = 0.15915494309189533576888376337251;

    int idx = blockIdx.x * blockDim.x + threadIdx.x;
    float mur = mu_raw[0], dmur = Dmu_raw[0], t0mur = T0mu_raw[0];
    float lyr = Ly_raw[0], xorw = xo_raw[0], yorw = yo_raw[0];

    if (idx < GEN_A) {
        int cg = idx / NM, m = idx - cg * NM;      // consecutive idx -> consecutive m
        float A, w, sg;
        mode_const(m, mur, dmur, t0mur, lyr, xorw, yorw, A, w, sg);
        #pragma unroll
        for (int i = 0; i < CGRP; ++i) {
            int c  = cg * CGRP + i;
            int t0 = c * DT;
            double ph = (double)t0 * (double)w * Kd;
            double q  = rint(ph * I2PI);
            float  r  = (float)fma(-q, TWO_PI, ph);
            float s0, c0;
            __sincosf(r, &s0, &c0);
            float env = A * __expf(-sg * (float)(t0 - 1) * KF);
            statePair[(size_t)c * NM + m] = make_float2(env * s0, env * c0);
        }
    } else if (idx < GEN_A + GEN_B) {
        int j = idx - GEN_A;
        int m = j >> 3, dtg = j & 7;
        float A, w, sg;
        mode_const(m, mur, dmur, t0mur, lyr, xorw, yorw, A, w, sg);
        (void)A;
        #pragma unroll
        for (int i = 0; i < 8; ++i) {
            int dt = dtg * 8 + i;
            double ph = (double)dt * (double)w * Kd;
            double q  = rint(ph * I2PI);
            float  r  = (float)fma(-q, TWO_PI, ph);
            float sr, cr;
            __sincosf(r, &sr, &cr);
            float dec = __expf(-sg * (float)dt * KF);
            cdsdR[m * DT + dt] = dec * cr;
            cdsdI[m * DT + dt] = dec * sr;
        }
    } else if (idx == GEN_A + GEN_B) {
        cnt[0] = 0u;
        peakBits[0] = 0u;
    }
}

// partial[y][64c+dt] = sum_{m in tile y} S*Re(r^dt) + C*Im(r^dt); lane = dt.
// Plain coalesced stores, NO atomics, NO fence (R11's 2200 device-scope
// fences were the 230us). Tile LDS m-major: 2-way bank alias = free.
__global__ __launch_bounds__(256) void gemm_kernel(
    const float2* __restrict__ statePair,
    const float* __restrict__ cdsdR, const float* __restrict__ cdsdI,
    float* __restrict__ partial)
{
    __shared__ float tR[MB * DT], tI[MB * DT];    // 16 KB + 16 KB
    const int tid = threadIdx.x;
    const int mBase = blockIdx.y * MB;

    {   // stage tiles: contiguous 16 KB each, float4-coalesced
        const float4* sR = (const float4*)(cdsdR + mBase * DT);
        const float4* sI = (const float4*)(cdsdI + mBase * DT);
        float4* dR = (float4*)tR;
        float4* dI = (float4*)tI;
        #pragma unroll
        for (int i = 0; i < (MB * DT / 4) / 256; ++i) {
            dR[i * 256 + tid] = sR[i * 256 + tid];
            dI[i * 256 + tid] = sI[i * 256 + tid];
        }
    }
    __syncthreads();

    const int wave = tid >> 6, lane = tid & 63;
    const int c0 = blockIdx.x * CB + wave * 4;
    const float2* r0 = statePair + (size_t)c0 * NM + mBase;
    const float2* r1 = r0 + NM;
    const float2* r2 = r0 + 2 * (size_t)NM;
    const float2* r3 = r0 + 3 * (size_t)NM;

    float a0 = 0.0f, a1 = 0.0f, a2 = 0.0f, a3 = 0.0f;
    #pragma unroll 8
    for (int m = 0; m < MB; m += 2) {
        float wR0 = tR[m * DT + lane],       wI0 = tI[m * DT + lane];
        float wR1 = tR[(m + 1) * DT + lane], wI1 = tI[(m + 1) * DT + lane];
        float4 s0 = *(const float4*)(r0 + m);   // {S_m, C_m, S_m+1, C_m+1}
        float4 s1 = *(const float4*)(r1 + m);
        float4 s2 = *(const float4*)(r2 + m);
        float4 s3 = *(const float4*)(r3 + m);
        a0 = __fmaf_rn(s0.x, wR0, a0); a0 = __fmaf_rn(s0.y, wI0, a0);
        a0 = __fmaf_rn(s0.z, wR1, a0); a0 = __fmaf_rn(s0.w, wI1, a0);
        a1 = __fmaf_rn(s1.x, wR0, a1); a1 = __fmaf_rn(s1.y, wI0, a1);
        a1 = __fmaf_rn(s1.z, wR1, a1); a1 = __fmaf_rn(s1.w, wI1, a1);
        a2 = __fmaf_rn(s2.x, wR0, a2); a2 = __fmaf_rn(s2.y, wI0, a2);
        a2 = __fmaf_rn(s2.z, wR1, a2); a2 = __fmaf_rn(s2.w, wI1, a2);
        a3 = __fmaf_rn(s3.x, wR0, a3); a3 = __fmaf_rn(s3.y, wI0, a3);
        a3 = __fmaf_rn(s3.z, wR1, a3); a3 = __fmaf_rn(s3.w, wI1, a3);
    }

    float* p = partial + (size_t)blockIdx.y * NCHP + c0 * DT + lane;
    p[0]      = a0;
    p[DT]     = a1;
    p[2 * DT] = a2;
    p[3 * DT] = a3;
}

// One kernel: out[t] = sum_y partial[y][t]; per-block peak via atomicMax on
// float bits; last of 87 blocks (counter + fence — cheap at this block count)
// divides through by the global peak.
__global__ __launch_bounds__(256) void reduce_norm_kernel(
    const float* __restrict__ partial, float* __restrict__ out,
    unsigned int* __restrict__ cnt, unsigned int* __restrict__ peakBits, int T)
{
    const int tid = threadIdx.x;
    int t = blockIdx.x * 256 + tid;

    float v = 0.0f;
    if (t < T) {
        float b0 = 0.0f, b1 = 0.0f, b2 = 0.0f, b3 = 0.0f;
        const float* p = partial + t;
        #pragma unroll 5
        for (int y = 0; y < MGY; y += 4) {
            b0 += p[(size_t)(y    ) * NCHP];
            b1 += p[(size_t)(y + 1) * NCHP];
            b2 += p[(size_t)(y + 2) * NCHP];
            b3 += p[(size_t)(y + 3) * NCHP];
        }
        v = (b0 + b1) + (b2 + b3);
        out[t] = v;
    }

    // block peak
    float mx = fabsf(v);
    #pragma unroll
    for (int off = 32; off > 0; off >>= 1)
        mx = fmaxf(mx, __shfl_xor(mx, off, 64));
    __shared__ float red[4];
    __shared__ int sLast;
    const int wave = tid >> 6, lane = tid & 63;
    if (lane == 0) red[wave] = mx;
    __syncthreads();
    if (tid == 0) {
        float m = fmaxf(fmaxf(red[0], red[1]), fmaxf(red[2], red[3]));
        atomicMax(peakBits, __float_as_uint(m));   // all values >= 0
    }
    __threadfence();                                // release out[] + peak
    __syncthreads();
    if (tid == 0) {
        unsigned int old = atomicAdd(cnt, 1u);
        sLast = (old == gridDim.x - 1) ? 1 : 0;
    }
    __syncthreads();
    if (sLast) {
        __threadfence();                            // acquire others' out[]
        float pk = __uint_as_float(atomicMax(peakBits, 0u)) + 1e-8f;
        for (int i = tid; i < T; i += 256)
            out[i] = __fdiv_rn(out[i], pk);
    }
}

extern "C" void kernel_launch(void* const* d_in, const int* in_sizes, int n_in,
                              void* d_out, int out_size, void* d_ws, size_t ws_size,
                              hipStream_t stream)
{
    const float* mu   = (const float*)d_in[0];
    const float* Dmu  = (const float*)d_in[1];
    const float* T0mu = (const float*)d_in[2];
    const float* Lyr  = (const float*)d_in[3];
    const float* xor_ = (const float*)d_in[4];
    const float* yor_ = (const float*)d_in[5];
    float* out = (float*)d_out;

    float2* statePair = (float2*)d_ws;                          // 18.0 MB
    float*  cdsdR     = (float*)(statePair + (size_t)NCH * NM); // 1.64 MB
    float*  cdsdI     = cdsdR + (size_t)NM * DT;                // 1.64 MB
    float*  partial   = cdsdI + (size_t)NM * DT;                // 100*NCHP*4 = 9.04 MB
    unsigned int* cnt      = (unsigned int*)(partial + (size_t)MGY * NCHP);
    unsigned int* peakBits = cnt + 1;

    int T = out_size;
    int genItems = GEN_A + GEN_B + 1;

    gen_kernel<<<(genItems + 255) / 256, 256, 0, stream>>>(
        mu, Dmu, T0mu, Lyr, xor_, yor_, statePair, cdsdR, cdsdI, cnt, peakBits);
    gemm_kernel<<<dim3(NCH / CB, MGY), 256, 0, stream>>>(
        statePair, cdsdR, cdsdI, partial);
    reduce_norm_kernel<<<(T + 255) / 256, 256, 0, stream>>>(
        partial, out, cnt, peakBits, T);
}